// Round 3
// baseline (395.986 us; speedup 1.0000x reference)
//
#include <hip/hip_runtime.h>
#include <math.h>

#define DM 256
#define LSEQ 2048
#define BATCH 8
#define NLAYER 8
#define EMAX 192
#define LN_EPS 1e-5f
#define BM 32
#define KC 64
#define NCH 4          // DM / KC
#define YPAD 260

typedef float f32x4 __attribute__((ext_vector_type(4)));
typedef short bf16x8 __attribute__((ext_vector_type(8)));
typedef unsigned short u16;
typedef unsigned short u16x4 __attribute__((ext_vector_type(4)));
typedef unsigned short u16x8 __attribute__((ext_vector_type(8)));

__device__ __forceinline__ float gelu_exact(float v) {
    return 0.5f * v * (1.f + erff(v * 0.70710678118654752f));
}

// split fp32 -> bf16 hi (truncated, exact-subtractable) + bf16 lo (RNE of remainder)
__device__ __forceinline__ void split2(float g, u16& hi, u16& lo) {
    unsigned u = __float_as_uint(g);
    hi = (u16)(u >> 16);
    float fh = __uint_as_float(u & 0xFFFF0000u);
    float r = g - fh;
    unsigned v = __float_as_uint(r);
    v = v + 0x7FFFu + ((v >> 16) & 1u);
    lo = (u16)(v >> 16);
}

// ---------------- pre-split pW (all layers) into bf16 hi/lo ----------------
__global__ void k_prepW(const float* __restrict__ pW, u16* __restrict__ pWh,
                        u16* __restrict__ pWl) {
    int i = (blockIdx.x * blockDim.x + threadIdx.x) * 4;
    float4 w = *(const float4*)&pW[i];
    u16 h0, l0, h1, l1, h2, l2, h3, l3;
    split2(w.x, h0, l0);
    split2(w.y, h1, l1);
    split2(w.z, h2, l2);
    split2(w.w, h3, l3);
    u16x4 vh = {h0, h1, h2, h3};
    u16x4 vl = {l0, l1, l2, l3};
    *(u16x4*)&pWh[i] = vh;
    *(u16x4*)&pWl[i] = vl;
}

// ---------------- init: h[b,t,c] = x[b,t,0]*inW[c] + inb[c] ----------------
__global__ void k_init(const float* __restrict__ x, const float* __restrict__ inW,
                       const float* __restrict__ inb, float* __restrict__ h) {
    int i4 = blockIdx.x * blockDim.x + threadIdx.x;
    int e = i4 * 4;
    int row = e >> 8;
    int c = e & 255;
    float xv = x[row];
    float4 w  = *(const float4*)&inW[c];
    float4 bb = *(const float4*)&inb[c];
    float4 o;
    o.x = xv * w.x + bb.x;
    o.y = xv * w.y + bb.y;
    o.z = xv * w.z + bb.z;
    o.w = xv * w.w + bb.w;
    *(float4*)&h[e] = o;
}

// ---------------- prep0: logA/CB all layers, P[0], zero P[1..7] + pooled ----------------
__global__ void k_prep0(const float* __restrict__ x, const float* __restrict__ inW,
                        const float* __restrict__ inb, const float* __restrict__ Ap,
                        const float* __restrict__ Bp, const float* __restrict__ Cp,
                        float* __restrict__ P_all, float* __restrict__ logA_all,
                        float* __restrict__ CB_all, float* __restrict__ pooled) {
    int b = blockIdx.x;
    int c = threadIdx.x;
    float A0 = 1.f / (1.f + expf(-Ap[c]));
    float iw = inW[c], ib = inb[c];
    const float* xb = x + b * LSEQ;
    float pw = 1.f, acc = 0.f;
    for (int t = 0; t <= EMAX; ++t) {
        acc += (xb[t] * iw + ib) * pw;
        pw *= A0;
    }
    P_all[b * DM + c] = acc;
    for (int l = 1; l < NLAYER; ++l) P_all[l * BATCH * DM + b * DM + c] = 0.f;
    for (int e = 0; e < 4; ++e) pooled[e * BATCH * DM + b * DM + c] = 0.f;
    if (b == 0) {
        for (int l = 0; l < NLAYER; ++l) {
            float Al = 1.f / (1.f + expf(-Ap[l * DM + c]));
            logA_all[l * DM + c] = logf(Al);
            CB_all[l * DM + c]   = Bp[l * DM + c] * Cp[l * DM + c];
        }
    }
}

// ---------------- fused MFMA layer kernel ----------------
// BM=32 rows/block, 256 threads = 4 waves (wave wv owns 64-col slice), KC=64, A dbuf in LDS,
// B (pre-split bf16 hi/lo) loaded global->reg, XOR-swizzled A LDS (T2), reg prefetch (T14).
__global__ __launch_bounds__(256, 3) void k_gemm(
    const float* h, float* hout,
    const u16* __restrict__ pWh, const u16* __restrict__ pWl,
    const float* __restrict__ pb,
    const float* __restrict__ lng, const float* __restrict__ lnb,
    const float* __restrict__ Dp,
    const float* __restrict__ P, const float* __restrict__ logA,
    const float* __restrict__ CB,
    const float* __restrict__ logA_next, float* __restrict__ P_next,
    float* __restrict__ pooled, int exitSlot)
{
    // layout: Ah buf0 @0, Ah buf1 @4096, Al buf0 @8192, Al buf1 @12288 (16KB stage)
    // epilogue aliases: Y f32[32][YPAD] @0 (33280B), csumb f32[4][256] @33280
    __shared__ __align__(16) char smem[37376];

    int tid  = threadIdx.x;
    int brow = blockIdx.x * BM;
    int b    = brow >> 11;
    int lane = tid & 63;
    int wv   = tid >> 6;              // 0..3 => col-slice
    int fr   = lane & 15;
    int fq   = lane >> 4;

    f32x4 acc[2][4];
#pragma unroll
    for (int m = 0; m < 2; ++m)
#pragma unroll
        for (int n = 0; n < 4; ++n) acc[m][n] = (f32x4){0.f, 0.f, 0.f, 0.f};

    // staging map: thread -> (row, 16B k-unit)
    int srow = tid >> 3;              // 0..31
    int sku  = tid & 7;               // 0..7 (8 bf16 each)
    int gr_s = brow + srow;
    int u_s  = (LSEQ - 1) - (gr_s & (LSEQ - 1));
    const float* hbase = &h[gr_s * DM + sku * 8];
    char* sdst = smem + srow * 128 + ((sku ^ (srow & 7)) << 4);

    // prologue: load chunk 0
    float4 cura = *(const float4*)&hbase[0];
    float4 curb = *(const float4*)&hbase[4];

    for (int ch = 0; ch < NCH; ++ch) {
        int kk = ch * 64 + sku * 8;
        // ---- gelu(D*h + conv-tail), split, write LDS (swizzled) ----
        {
            float4 d0 = *(const float4*)&Dp[kk];
            float4 d1 = *(const float4*)&Dp[kk + 4];
            float vv[8];
            vv[0] = cura.x * d0.x; vv[1] = cura.y * d0.y;
            vv[2] = cura.z * d0.z; vv[3] = cura.w * d0.w;
            vv[4] = curb.x * d1.x; vv[5] = curb.y * d1.y;
            vv[6] = curb.z * d1.z; vv[7] = curb.w * d1.w;
            if (u_s <= EMAX) {
                float uf = (float)u_s;
                float4 la0 = *(const float4*)&logA[kk];
                float4 la1 = *(const float4*)&logA[kk + 4];
                float4 cb0 = *(const float4*)&CB[kk];
                float4 cb1 = *(const float4*)&CB[kk + 4];
                float4 P0  = *(const float4*)&P[b * DM + kk];
                float4 P1  = *(const float4*)&P[b * DM + kk + 4];
                vv[0] += cb0.x * expf(uf * la0.x) * P0.x;
                vv[1] += cb0.y * expf(uf * la0.y) * P0.y;
                vv[2] += cb0.z * expf(uf * la0.z) * P0.z;
                vv[3] += cb0.w * expf(uf * la0.w) * P0.w;
                vv[4] += cb1.x * expf(uf * la1.x) * P1.x;
                vv[5] += cb1.y * expf(uf * la1.y) * P1.y;
                vv[6] += cb1.z * expf(uf * la1.z) * P1.z;
                vv[7] += cb1.w * expf(uf * la1.w) * P1.w;
            }
            u16 sh[8], sl[8];
#pragma unroll
            for (int j = 0; j < 8; ++j) split2(gelu_exact(vv[j]), sh[j], sl[j]);
            u16x8 vh = {sh[0], sh[1], sh[2], sh[3], sh[4], sh[5], sh[6], sh[7]};
            u16x8 vl = {sl[0], sl[1], sl[2], sl[3], sl[4], sl[5], sl[6], sl[7]};
            char* d = sdst + (ch & 1) * 4096;
            *(u16x8*)d = vh;
            *(u16x8*)(d + 8192) = vl;
        }
        // ---- prefetch next chunk's h into regs (hides HBM under MFMA) ----
        if (ch + 1 < NCH) {
            cura = *(const float4*)&hbase[(ch + 1) * 64];
            curb = *(const float4*)&hbase[(ch + 1) * 64 + 4];
        }
        __syncthreads();
        // ---- MFMA: 2 k-steps of 32 ----
#pragma unroll
        for (int ks = 0; ks < 2; ++ks) {
            bf16x8 ah[2], al[2], bh[4], bl[4];
#pragma unroll
            for (int m = 0; m < 2; ++m) {
                int r = m * 16 + fr;
                const char* a = smem + (ch & 1) * 4096 + r * 128 +
                                (((ks * 4 + fq) ^ (r & 7)) << 4);
                ah[m] = *(const bf16x8*)a;
                al[m] = *(const bf16x8*)(a + 8192);
            }
#pragma unroll
            for (int n = 0; n < 4; ++n) {
                int goff = (wv * 64 + n * 16 + fr) * DM + ch * 64 + ks * 32 + fq * 8;
                bh[n] = *(const bf16x8*)&pWh[goff];
                bl[n] = *(const bf16x8*)&pWl[goff];
            }
#pragma unroll
            for (int m = 0; m < 2; ++m)
#pragma unroll
                for (int n = 0; n < 4; ++n) {
                    acc[m][n] = __builtin_amdgcn_mfma_f32_16x16x32_bf16(ah[m], bh[n], acc[m][n], 0, 0, 0);
                    acc[m][n] = __builtin_amdgcn_mfma_f32_16x16x32_bf16(ah[m], bl[n], acc[m][n], 0, 0, 0);
                    acc[m][n] = __builtin_amdgcn_mfma_f32_16x16x32_bf16(al[m], bh[n], acc[m][n], 0, 0, 0);
                }
        }
    }
    __syncthreads();

    // ---- epilogue: Y transpose, residual + LN + store + pooled + P_next ----
    float* Y = (float*)smem;
#pragma unroll
    for (int m = 0; m < 2; ++m)
#pragma unroll
        for (int n = 0; n < 4; ++n)
#pragma unroll
            for (int r = 0; r < 4; ++r)
                Y[(m * 16 + fq * 4 + r) * YPAD + wv * 64 + n * 16 + fr] = acc[m][n][r];
    __syncthreads();

    int c0 = lane * 4;
    float4 pbv = *(const float4*)&pb[c0];
    float4 lg  = *(const float4*)&lng[c0];
    float4 lb  = *(const float4*)&lnb[c0];
    float cs0 = 0.f, cs1 = 0.f, cs2 = 0.f, cs3 = 0.f;
#pragma unroll
    for (int i = 0; i < 8; ++i) {
        int lr = wv * 8 + i;
        int gr = brow + lr;
        float4 o2 = *(float4*)&Y[lr * YPAD + c0];
        float4 hv = *(const float4*)&h[gr * DM + c0];
        float y0 = hv.x + o2.x + pbv.x;
        float y1 = hv.y + o2.y + pbv.y;
        float y2 = hv.z + o2.z + pbv.z;
        float y3 = hv.w + o2.w + pbv.w;
        float s  = y0 + y1 + y2 + y3;
        float ss = y0 * y0 + y1 * y1 + y2 * y2 + y3 * y3;
#pragma unroll
        for (int off = 1; off < 64; off <<= 1) {
            s  += __shfl_xor(s, off);
            ss += __shfl_xor(ss, off);
        }
        float mean = s * (1.f / 256.f);
        float var  = ss * (1.f / 256.f) - mean * mean;
        float rstd = rsqrtf(var + LN_EPS);
        float o0 = (y0 - mean) * rstd * lg.x + lb.x;
        float o1 = (y1 - mean) * rstd * lg.y + lb.y;
        float o2o = (y2 - mean) * rstd * lg.z + lb.z;
        float o3 = (y3 - mean) * rstd * lg.w + lb.w;
        float4 ov = {o0, o1, o2o, o3};
        *(float4*)&hout[gr * DM + c0] = ov;
        cs0 += o0; cs1 += o1; cs2 += o2o; cs3 += o3;
        int t = gr & (LSEQ - 1);
        if (P_next != nullptr && t <= EMAX) {
            float tf = (float)t;
            float4 la = *(const float4*)&logA_next[c0];
            atomicAdd(&P_next[b * DM + c0 + 0], o0  * expf(tf * la.x));
            atomicAdd(&P_next[b * DM + c0 + 1], o1  * expf(tf * la.y));
            atomicAdd(&P_next[b * DM + c0 + 2], o2o * expf(tf * la.z));
            atomicAdd(&P_next[b * DM + c0 + 3], o3  * expf(tf * la.w));
        }
    }

    if (exitSlot >= 0) {
        float* csumb = (float*)(smem + 33280);
        __syncthreads();
        csumb[wv * DM + c0 + 0] = cs0;
        csumb[wv * DM + c0 + 1] = cs1;
        csumb[wv * DM + c0 + 2] = cs2;
        csumb[wv * DM + c0 + 3] = cs3;
        __syncthreads();
        if (tid < 64) {
            int cc = tid * 4;
#pragma unroll
            for (int q = 0; q < 4; ++q) {
                float sm = 0.f;
#pragma unroll
                for (int w = 0; w < 4; ++w) sm += csumb[w * DM + cc + q];
                atomicAdd(&pooled[exitSlot * (BATCH * DM) + b * DM + cc + q], sm);
            }
        }
    }
}

// ---------------- head ----------------
__global__ void k_head(const float* __restrict__ pooled, const float* __restrict__ hW,
                       const float* __restrict__ hb, float* __restrict__ out) {
    int tid = threadIdx.x;
    if (tid >= 96) return;
    int e = tid / 24;
    int r = tid % 24;
    int b = r / 3;
    int n = r % 3;
    const float* pv = &pooled[e * (BATCH * DM) + b * DM];
    const float* wv = &hW[(e * 3 + n) * DM];
    float acc = 0.f;
    for (int c = 0; c < DM; ++c) acc += pv[c] * wv[c];
    out[e * 24 + b * 3 + n] = acc * (1.f / (float)LSEQ) + hb[e * 3 + n];
}

extern "C" void kernel_launch(void* const* d_in, const int* in_sizes, int n_in,
                              void* d_out, int out_size, void* d_ws, size_t ws_size,
                              hipStream_t stream) {
    const float* x   = (const float*)d_in[0];
    const float* inW = (const float*)d_in[1];
    const float* inb = (const float*)d_in[2];
    const float* Ap  = (const float*)d_in[3];
    const float* Bp  = (const float*)d_in[4];
    const float* Cp  = (const float*)d_in[5];
    const float* Dp  = (const float*)d_in[6];
    const float* pW  = (const float*)d_in[7];
    const float* pb  = (const float*)d_in[8];
    const float* lng = (const float*)d_in[9];
    const float* lnb = (const float*)d_in[10];
    const float* hW  = (const float*)d_in[11];
    const float* hb  = (const float*)d_in[12];
    float* out = (float*)d_out;

    float* ws = (float*)d_ws;
    float* h        = ws;                            // 4194304 f32
    float* P_all    = h + BATCH * LSEQ * DM;         // 16384
    float* logA_all = P_all + NLAYER * BATCH * DM;   // 2048
    float* CB_all   = logA_all + NLAYER * DM;        // 2048
    float* pooled   = CB_all + NLAYER * DM;          // 8192
    u16* pWh        = (u16*)(pooled + 4 * BATCH * DM);       // 524288 u16
    u16* pWl        = pWh + NLAYER * DM * DM;                // 524288 u16

    k_prepW<<<(NLAYER * DM * DM) / 1024, 256, 0, stream>>>(pW, pWh, pWl);
    k_prep0<<<BATCH, 256, 0, stream>>>(x, inW, inb, Ap, Bp, Cp,
                                       P_all, logA_all, CB_all, pooled);
    k_init<<<4096, 256, 0, stream>>>(x, inW, inb, h);
    for (int l = 0; l < NLAYER; ++l) {
        int ex = (l == 1) ? 0 : (l == 3) ? 1 : (l == 5) ? 2 : (l == 7) ? 3 : -1;
        const float* lan = (l < NLAYER - 1) ? (logA_all + (l + 1) * DM) : nullptr;
        float* pn        = (l < NLAYER - 1) ? (P_all + (l + 1) * BATCH * DM) : nullptr;
        k_gemm<<<(BATCH * LSEQ) / BM, 256, 0, stream>>>(
            h, h, pWh + l * DM * DM, pWl + l * DM * DM, pb + l * DM,
            lng + l * DM, lnb + l * DM, Dp + l * DM,
            P_all + l * BATCH * DM, logA_all + l * DM, CB_all + l * DM,
            lan, pn, pooled, ex);
    }
    k_head<<<1, 128, 0, stream>>>(pooled, hW, hb, out);
}